// Round 2
// baseline (4957.734 us; speedup 1.0000x reference)
//
#include <hip/hip_runtime.h>

namespace {
constexpr int B = 8;
constexpr int N = 1568;
constexpr int C = 768;
constexpr int H = 12;
constexpr int D = 64;
constexpr long long BHND = (long long)B * H * N * D;   // 9,633,792 floats per tensor
constexpr int NT = (N + 63) / 64;                      // 25 key tiles
}

// ---------------------------------------------------------------------------
// QKV GEMM: out(m,j) = sum_k x[m,k]*W[j,k] + bias[j]
// scattered to ws[sel][b][h][n][d] with sel=j/768, h=(j%768)/64, d=j%64
// 128x128 tile, BK=16, 256 threads, 8x8 micro-tile per thread.
// ---------------------------------------------------------------------------
__global__ __launch_bounds__(256) void qkv_gemm_kernel(
    const float* __restrict__ x, const float* __restrict__ W,
    const float* __restrict__ bias, float* __restrict__ ws)
{
    __shared__ float As[16][136];   // [k][m]
    __shared__ float Bs[16][136];   // [k][j]

    const int tid = threadIdx.x;
    const int tx = tid & 15;        // output col group
    const int ty = tid >> 4;        // output row group
    const int m0 = blockIdx.x * 128;
    const int j0 = blockIdx.y * 128;

    const int srow = tid >> 2;            // 0..63
    const int sk4  = (tid & 3) << 2;      // 0,4,8,12

    const float* Ap = x + (size_t)(m0 + srow) * C + sk4;
    const float* Bp = W + (size_t)(j0 + srow) * C + sk4;

    float acc[8][8] = {};

    for (int kb = 0; kb < C; kb += 16) {
        const float4 a0 = *(const float4*)(Ap + kb);
        const float4 a1 = *(const float4*)(Ap + (size_t)64 * C + kb);
        const float4 b0 = *(const float4*)(Bp + kb);
        const float4 b1 = *(const float4*)(Bp + (size_t)64 * C + kb);
        __syncthreads();
        As[sk4+0][srow]    = a0.x; As[sk4+1][srow]    = a0.y;
        As[sk4+2][srow]    = a0.z; As[sk4+3][srow]    = a0.w;
        As[sk4+0][srow+64] = a1.x; As[sk4+1][srow+64] = a1.y;
        As[sk4+2][srow+64] = a1.z; As[sk4+3][srow+64] = a1.w;
        Bs[sk4+0][srow]    = b0.x; Bs[sk4+1][srow]    = b0.y;
        Bs[sk4+2][srow]    = b0.z; Bs[sk4+3][srow]    = b0.w;
        Bs[sk4+0][srow+64] = b1.x; Bs[sk4+1][srow+64] = b1.y;
        Bs[sk4+2][srow+64] = b1.z; Bs[sk4+3][srow+64] = b1.w;
        __syncthreads();
        #pragma unroll
        for (int k = 0; k < 16; ++k) {
            const float4 av0 = *(const float4*)&As[k][ty << 3];
            const float4 av1 = *(const float4*)&As[k][(ty << 3) + 4];
            const float4 bv0 = *(const float4*)&Bs[k][tx << 3];
            const float4 bv1 = *(const float4*)&Bs[k][(tx << 3) + 4];
            const float ar[8] = {av0.x, av0.y, av0.z, av0.w, av1.x, av1.y, av1.z, av1.w};
            const float br[8] = {bv0.x, bv0.y, bv0.z, bv0.w, bv1.x, bv1.y, bv1.z, bv1.w};
            #pragma unroll
            for (int i = 0; i < 8; ++i)
                #pragma unroll
                for (int j = 0; j < 8; ++j)
                    acc[i][j] += ar[i] * br[j];
        }
    }

    const float4 bias40 = *(const float4*)(bias + j0 + (tx << 3));
    const float4 bias41 = *(const float4*)(bias + j0 + (tx << 3) + 4);
    const float bb[8] = {bias40.x, bias40.y, bias40.z, bias40.w,
                         bias41.x, bias41.y, bias41.z, bias41.w};

    #pragma unroll
    for (int jh = 0; jh < 2; ++jh) {
        const int col = j0 + (tx << 3) + jh * 4;   // 4-aligned: inside one 64-block
        const int sel = col / C;
        const int rem = col % C;
        const int h   = rem >> 6;
        const int d   = rem & 63;
        float* dst0 = ws + (size_t)sel * BHND + (size_t)h * N * D + d;
        #pragma unroll
        for (int i = 0; i < 8; ++i) {
            const int m  = m0 + (ty << 3) + i;
            const int b_ = m / N;
            const int n_ = m % N;
            float4 o;
            o.x = acc[i][jh*4+0] + bb[jh*4+0];
            o.y = acc[i][jh*4+1] + bb[jh*4+1];
            o.z = acc[i][jh*4+2] + bb[jh*4+2];
            o.w = acc[i][jh*4+3] + bb[jh*4+3];
            *(float4*)(dst0 + ((size_t)b_ * H * N + (size_t)n_) * D) = o;
        }
    }
}

// ---------------------------------------------------------------------------
// Cosine attention, flash-style. One block = one (b*H+h, 64-row q-tile).
// Staging: 256 threads x 4 passes, 16 threads/row -> full 64x64 tile; L2
// normalization fused (16-lane shfl reduce = one full row).
// Scores bounded by 1 => softmax via exp(s) directly, no running max.
// LDS: 4 x [64][64] fp32 = 64 KiB. XOR swizzles on Ks/Vs/Ss per-lane-row reads.
// ---------------------------------------------------------------------------
__global__ __launch_bounds__(256) void attn_kernel(
    const float* __restrict__ ws, float* __restrict__ out)
{
    __shared__ float Qs[64][64];
    __shared__ float Ks[64][64];   // [c][d ^ (((c>>2)&7)<<2)]
    __shared__ float Vs[64][64];   // [c][d ^ (((c   )&7)<<2)]
    __shared__ float Ss[64][64];   // [r][j ^ (((r   )&7)<<2)]

    const int tid = threadIdx.x;
    const int tx = tid & 15;     // score col group (4 cols)
    const int ty = tid >> 4;     // score row group (4 rows)
    const int qt = blockIdx.x;
    const int bh = blockIdx.y;   // b*H + h

    const float* qp = ws + (size_t)bh * N * D;
    const float* kp = ws + (size_t)BHND + (size_t)bh * N * D;
    const float* vp = ws + 2 * (size_t)BHND + (size_t)bh * N * D;

    const int r16 = tid >> 4;          // staging row within 16-row group
    const int c4  = (tid & 15) << 2;   // staging d-offset 0..60

    // ---- stage + normalize Q tile (once per block) ----
    #pragma unroll
    for (int p = 0; p < 4; ++p) {
        const int row = (p << 4) + r16;
        const int n = qt * 64 + row;
        float4 q = make_float4(0.f, 0.f, 0.f, 0.f);
        if (n < N) q = *(const float4*)(qp + (size_t)n * D + c4);
        float ssq = q.x*q.x + q.y*q.y + q.z*q.z + q.w*q.w;
        ssq += __shfl_xor(ssq, 1);
        ssq += __shfl_xor(ssq, 2);
        ssq += __shfl_xor(ssq, 4);
        ssq += __shfl_xor(ssq, 8);
        const float inv = 1.f / fmaxf(sqrtf(ssq), 1e-12f);
        q.x *= inv; q.y *= inv; q.z *= inv; q.w *= inv;
        *(float4*)&Qs[row][c4] = q;
    }

    float acc[4][4] = {};
    float denom[4] = {};
    const int xmK = (tx & 7) << 2;              // K read swizzle mask
    const int xmS = (((ty << 2) & 7)) << 2;     // placeholder (recomputed per i)

    for (int kt = 0; kt < NT; ++kt) {
        // ---- load + normalize K, load V into registers ----
        float4 kq[4], vq[4];
        #pragma unroll
        for (int p = 0; p < 4; ++p) {
            const int row = (p << 4) + r16;
            const int n = kt * 64 + row;
            float4 kv = make_float4(0.f,0.f,0.f,0.f);
            float4 vv = make_float4(0.f,0.f,0.f,0.f);
            if (n < N) {
                kv = *(const float4*)(kp + (size_t)n * D + c4);
                vv = *(const float4*)(vp + (size_t)n * D + c4);
            }
            float ssq = kv.x*kv.x + kv.y*kv.y + kv.z*kv.z + kv.w*kv.w;
            ssq += __shfl_xor(ssq, 1);
            ssq += __shfl_xor(ssq, 2);
            ssq += __shfl_xor(ssq, 4);
            ssq += __shfl_xor(ssq, 8);
            const float inv = 1.f / fmaxf(sqrtf(ssq), 1e-12f);
            kv.x *= inv; kv.y *= inv; kv.z *= inv; kv.w *= inv;
            kq[p] = kv; vq[p] = vv;
        }

        __syncthreads();   // previous PV (reads Vs/Ss) done
        #pragma unroll
        for (int p = 0; p < 4; ++p) {
            const int row = (p << 4) + r16;
            *(float4*)&Ks[row][c4 ^ (((row >> 2) & 7) << 2)] = kq[p];
            *(float4*)&Vs[row][c4 ^ ((row & 7) << 2)]        = vq[p];
        }
        __syncthreads();

        // ---- S = Q . K^T (4x4 per thread, float4 over d) ----
        float s[4][4] = {};
        #pragma unroll
        for (int d4 = 0; d4 < 64; d4 += 4) {
            const float4 q0 = *(const float4*)&Qs[(ty<<2)+0][d4];
            const float4 q1 = *(const float4*)&Qs[(ty<<2)+1][d4];
            const float4 q2 = *(const float4*)&Qs[(ty<<2)+2][d4];
            const float4 q3 = *(const float4*)&Qs[(ty<<2)+3][d4];
            const float4 k0 = *(const float4*)&Ks[(tx<<2)+0][d4 ^ xmK];
            const float4 k1 = *(const float4*)&Ks[(tx<<2)+1][d4 ^ xmK];
            const float4 k2 = *(const float4*)&Ks[(tx<<2)+2][d4 ^ xmK];
            const float4 k3 = *(const float4*)&Ks[(tx<<2)+3][d4 ^ xmK];
            const float Qr[4][4] = {{q0.x,q0.y,q0.z,q0.w},{q1.x,q1.y,q1.z,q1.w},
                                    {q2.x,q2.y,q2.z,q2.w},{q3.x,q3.y,q3.z,q3.w}};
            const float Kr[4][4] = {{k0.x,k0.y,k0.z,k0.w},{k1.x,k1.y,k1.z,k1.w},
                                    {k2.x,k2.y,k2.z,k2.w},{k3.x,k3.y,k3.z,k3.w}};
            #pragma unroll
            for (int i = 0; i < 4; ++i)
                #pragma unroll
                for (int j = 0; j < 4; ++j)
                    s[i][j] += Qr[i][0]*Kr[j][0] + Qr[i][1]*Kr[j][1]
                             + Qr[i][2]*Kr[j][2] + Qr[i][3]*Kr[j][3];
        }

        // ---- p = exp(s), mask OOB cols, accumulate denominator, stage P ----
        const int cb = kt * 64 + (tx << 2);
        #pragma unroll
        for (int i = 0; i < 4; ++i) {
            float4 pr;
            pr.x = (cb + 0 < N) ? __expf(s[i][0]) : 0.f;
            pr.y = (cb + 1 < N) ? __expf(s[i][1]) : 0.f;
            pr.z = (cb + 2 < N) ? __expf(s[i][2]) : 0.f;
            pr.w = (cb + 3 < N) ? __expf(s[i][3]) : 0.f;
            denom[i] += pr.x + pr.y + pr.z + pr.w;
            const int row = (ty << 2) + i;
            *(float4*)&Ss[row][(tx << 2) ^ ((row & 7) << 2)] = pr;
        }
        __syncthreads();

        // ---- acc += P . V (float4 over j) ----
        #pragma unroll
        for (int i = 0; i < 4; ++i) {
            const int row = (ty << 2) + i;
            const int xm = (row & 7) << 2;
            #pragma unroll
            for (int jj4 = 0; jj4 < 64; jj4 += 4) {
                const float4 p = *(const float4*)&Ss[row][jj4 ^ xm];
                const float4 v0 = *(const float4*)&Vs[jj4+0][(tx<<2) ^ (((jj4+0)&7)<<2)];
                const float4 v1 = *(const float4*)&Vs[jj4+1][(tx<<2) ^ (((jj4+1)&7)<<2)];
                const float4 v2 = *(const float4*)&Vs[jj4+2][(tx<<2) ^ (((jj4+2)&7)<<2)];
                const float4 v3 = *(const float4*)&Vs[jj4+3][(tx<<2) ^ (((jj4+3)&7)<<2)];
                acc[i][0] += p.x*v0.x + p.y*v1.x + p.z*v2.x + p.w*v3.x;
                acc[i][1] += p.x*v0.y + p.y*v1.y + p.z*v2.y + p.w*v3.y;
                acc[i][2] += p.x*v0.z + p.y*v1.z + p.z*v2.z + p.w*v3.z;
                acc[i][3] += p.x*v0.w + p.y*v1.w + p.z*v2.w + p.w*v3.w;
            }
        }
    }

    // ---- finalize: reduce denom over the 16 tx lanes, divide, store ----
    const int b_ = bh / H;
    const int h_ = bh % H;
    #pragma unroll
    for (int i = 0; i < 4; ++i) {
        float dsum = denom[i];
        dsum += __shfl_xor(dsum, 1);
        dsum += __shfl_xor(dsum, 2);
        dsum += __shfl_xor(dsum, 4);
        dsum += __shfl_xor(dsum, 8);
        const int n = qt * 64 + (ty << 2) + i;
        if (n < N) {
            const float inv = 1.f / dsum;
            float4 o;
            o.x = acc[i][0] * inv; o.y = acc[i][1] * inv;
            o.z = acc[i][2] * inv; o.w = acc[i][3] * inv;
            *(float4*)(out + ((size_t)b_ * N + n) * C + (h_ << 6) + (tx << 2)) = o;
        }
    }
}

extern "C" void kernel_launch(void* const* d_in, const int* in_sizes, int n_in,
                              void* d_out, int out_size, void* d_ws, size_t ws_size,
                              hipStream_t stream) {
    const float* x    = (const float*)d_in[0];
    const float* Wq   = (const float*)d_in[1];
    const float* bq   = (const float*)d_in[2];
    float* out = (float*)d_out;
    float* ws  = (float*)d_ws;   // [3][B][H][N][D] fp32 = ~110.3 MiB

    qkv_gemm_kernel<<<dim3((B * N) / 128, (3 * C) / 128), 256, 0, stream>>>(x, Wq, bq, ws);
    attn_kernel<<<dim3(NT, B * H), 256, 0, stream>>>(ws, out);
}

// Round 3
// 768.109 us; speedup vs baseline: 6.4545x; 6.4545x over previous
//
#include <hip/hip_runtime.h>

typedef __attribute__((ext_vector_type(8))) short bf16x8;
typedef __attribute__((ext_vector_type(4))) float f32x4;
typedef __attribute__((ext_vector_type(4))) short short4v;

namespace {
constexpr int B = 8;
constexpr int N = 1568;
constexpr int C = 768;
constexpr int H = 12;
constexpr int D = 64;
constexpr long long BHND = (long long)B * H * N * D;   // 9,633,792 floats
constexpr int NT = 25;                                 // ceil(1568/64)
}

__device__ __forceinline__ ushort f2bf(float f) {
    union { float f; unsigned u; } a; a.f = f;
    unsigned u = a.u;
    u += 0x7FFF + ((u >> 16) & 1);   // round-to-nearest-even
    return (ushort)(u >> 16);
}
__device__ __forceinline__ float bf2f(ushort s) {
    union { float f; unsigned u; } a; a.u = ((unsigned)s) << 16;
    return a.f;
}

// ---------------------------------------------------------------------------
// QKV GEMM (fp32, at vector roofline). q,k scattered to [bh][n][d];
// v scattered TRANSPOSED to [bh][d][n] so attn can stage V rows like K rows.
// ---------------------------------------------------------------------------
__global__ __launch_bounds__(256) void qkv_gemm_kernel(
    const float* __restrict__ x, const float* __restrict__ W,
    const float* __restrict__ bias, float* __restrict__ ws)
{
    __shared__ float As[16][136];
    __shared__ float Bs[16][136];

    const int tid = threadIdx.x;
    const int tx = tid & 15;
    const int ty = tid >> 4;
    const int m0 = blockIdx.x * 128;
    const int j0 = blockIdx.y * 128;

    const int srow = tid >> 2;
    const int sk4  = (tid & 3) << 2;

    const float* Ap = x + (size_t)(m0 + srow) * C + sk4;
    const float* Bp = W + (size_t)(j0 + srow) * C + sk4;

    float acc[8][8] = {};

    for (int kb = 0; kb < C; kb += 16) {
        const float4 a0 = *(const float4*)(Ap + kb);
        const float4 a1 = *(const float4*)(Ap + (size_t)64 * C + kb);
        const float4 b0 = *(const float4*)(Bp + kb);
        const float4 b1 = *(const float4*)(Bp + (size_t)64 * C + kb);
        __syncthreads();
        As[sk4+0][srow]    = a0.x; As[sk4+1][srow]    = a0.y;
        As[sk4+2][srow]    = a0.z; As[sk4+3][srow]    = a0.w;
        As[sk4+0][srow+64] = a1.x; As[sk4+1][srow+64] = a1.y;
        As[sk4+2][srow+64] = a1.z; As[sk4+3][srow+64] = a1.w;
        Bs[sk4+0][srow]    = b0.x; Bs[sk4+1][srow]    = b0.y;
        Bs[sk4+2][srow]    = b0.z; Bs[sk4+3][srow]    = b0.w;
        Bs[sk4+0][srow+64] = b1.x; Bs[sk4+1][srow+64] = b1.y;
        Bs[sk4+2][srow+64] = b1.z; Bs[sk4+3][srow+64] = b1.w;
        __syncthreads();
        #pragma unroll
        for (int k = 0; k < 16; ++k) {
            const float4 av0 = *(const float4*)&As[k][ty << 3];
            const float4 av1 = *(const float4*)&As[k][(ty << 3) + 4];
            const float4 bv0 = *(const float4*)&Bs[k][tx << 3];
            const float4 bv1 = *(const float4*)&Bs[k][(tx << 3) + 4];
            const float ar[8] = {av0.x, av0.y, av0.z, av0.w, av1.x, av1.y, av1.z, av1.w};
            const float br[8] = {bv0.x, bv0.y, bv0.z, bv0.w, bv1.x, bv1.y, bv1.z, bv1.w};
            #pragma unroll
            for (int i = 0; i < 8; ++i)
                #pragma unroll
                for (int j = 0; j < 8; ++j)
                    acc[i][j] += ar[i] * br[j];
        }
    }

    const float4 bias40 = *(const float4*)(bias + j0 + (tx << 3));
    const float4 bias41 = *(const float4*)(bias + j0 + (tx << 3) + 4);
    const float bb[8] = {bias40.x, bias40.y, bias40.z, bias40.w,
                         bias41.x, bias41.y, bias41.z, bias41.w};

    #pragma unroll
    for (int jh = 0; jh < 2; ++jh) {
        const int col = j0 + (tx << 3) + jh * 4;   // 4 cols, same sel/h block
        const int sel = col / C;
        const int rem = col % C;
        const int h   = rem >> 6;
        const int d   = rem & 63;
        if (sel < 2) {
            float* dst0 = ws + (size_t)sel * BHND + (size_t)h * N * D + d;
            #pragma unroll
            for (int i = 0; i < 8; ++i) {
                const int m  = m0 + (ty << 3) + i;
                const int b_ = m / N;
                const int n_ = m % N;
                float4 o;
                o.x = acc[i][jh*4+0] + bb[jh*4+0];
                o.y = acc[i][jh*4+1] + bb[jh*4+1];
                o.z = acc[i][jh*4+2] + bb[jh*4+2];
                o.w = acc[i][jh*4+3] + bb[jh*4+3];
                *(float4*)(dst0 + ((size_t)b_ * H * N + (size_t)n_) * D) = o;
            }
        } else {
            // v transposed: [b][h][d][n]
            #pragma unroll
            for (int i = 0; i < 8; ++i) {
                const int m  = m0 + (ty << 3) + i;
                const int b_ = m / N;
                const int n_ = m % N;
                float* vb = ws + 2 * (size_t)BHND
                          + (((size_t)b_ * H + h) * D + d) * N + n_;
                vb[0]           = acc[i][jh*4+0] + bb[jh*4+0];
                vb[(size_t)N]   = acc[i][jh*4+1] + bb[jh*4+1];
                vb[(size_t)2*N] = acc[i][jh*4+2] + bb[jh*4+2];
                vb[(size_t)3*N] = acc[i][jh*4+3] + bb[jh*4+3];
            }
        }
    }
}

// ---------------------------------------------------------------------------
// Cosine attention with bf16 MFMA (16x16x32). One block = (bh, 64-q-tile),
// 4 waves, wave w owns q rows 16w..16w+15. All LDS tiles are [64][64] bf16,
// linear, XOR-swizzled: element (row, col) at col ^ ((row&7)<<3).
// All MFMA operand reads: row = lane&15, 8 contiguous k at (lane>>4)*8
// (self-consistent k-permutation; C/D layout col=lane&15,row=(lane>>4)*4+reg).
// Scores in [-1,1] => exp without max subtraction. Denominator per-lane
// accumulated, one 16-lane shfl reduce at the end.
// ---------------------------------------------------------------------------
__global__ __launch_bounds__(256) void attn_kernel(
    const float* __restrict__ ws, float* __restrict__ out)
{
    __shared__ ushort Qs[64][64];
    __shared__ ushort Ks[64][64];
    __shared__ ushort Vt[64][64];   // V^T: rows = d, cols = kv
    __shared__ ushort Ss[64][64];   // P:   rows = q, cols = kv (wave-private strips)

    const int tid = threadIdx.x;
    const int l   = tid & 63;
    const int w   = tid >> 6;       // wave 0..3
    const int l15 = l & 15;
    const int lg  = l >> 4;         // 0..3

    // XCD-aware mapping: all 25 q-tiles of one bh land on the same XCD slot.
    const int bid = blockIdx.x;                 // 0..2399
    const int qt  = (bid >> 3) % 25;
    const int bh  = (bid & 7) + 8 * ((bid >> 3) / 25);

    const float* qp  = ws + (size_t)bh * N * D;
    const float* kp  = ws + (size_t)BHND + (size_t)bh * N * D;
    const float* vtp = ws + 2 * (size_t)BHND + (size_t)bh * D * N;

    const int sr = tid >> 4;          // staging row-sub 0..15
    const int sc = (tid & 15) << 2;   // staging col 0,4,..,60

    // ---- stage Q (normalized, bf16, swizzled) ----
    #pragma unroll
    for (int p = 0; p < 4; ++p) {
        const int row = p * 16 + sr;
        const int n = qt * 64 + row;
        float4 q = {0.f, 0.f, 0.f, 0.f};
        if (n < N) q = *(const float4*)(qp + (size_t)n * D + sc);
        float ssq = q.x*q.x + q.y*q.y + q.z*q.z + q.w*q.w;
        ssq += __shfl_xor(ssq, 1); ssq += __shfl_xor(ssq, 2);
        ssq += __shfl_xor(ssq, 4); ssq += __shfl_xor(ssq, 8);
        const float inv = 1.f / fmaxf(sqrtf(ssq), 1e-12f);
        short4v o;
        o.x = (short)f2bf(q.x * inv); o.y = (short)f2bf(q.y * inv);
        o.z = (short)f2bf(q.z * inv); o.w = (short)f2bf(q.w * inv);
        *(short4v*)&Qs[row][sc ^ ((row & 7) << 3)] = o;
    }
    __syncthreads();

    // Q fragments (block-persistent)
    bf16x8 qf[2];
    {
        const int qrow = w * 16 + l15;
        const int m = (qrow & 7) << 3;
        qf[0] = *(const bf16x8*)&Qs[qrow][(lg * 8) ^ m];
        qf[1] = *(const bf16x8*)&Qs[qrow][(32 + lg * 8) ^ m];
    }

    f32x4 o_acc[4] = {};            // [d-tile][reg]
    float denom[4] = {0.f, 0.f, 0.f, 0.f};

    for (int kt = 0; kt < NT; ++kt) {
        // ---- global loads -> regs (K normalized) ----
        short4v kqv[4], vqv[4];
        #pragma unroll
        for (int p = 0; p < 4; ++p) {
            const int row = p * 16 + sr;
            {
                const int n = kt * 64 + row;
                float4 v = {0.f, 0.f, 0.f, 0.f};
                if (n < N) v = *(const float4*)(kp + (size_t)n * D + sc);
                float ssq = v.x*v.x + v.y*v.y + v.z*v.z + v.w*v.w;
                ssq += __shfl_xor(ssq, 1); ssq += __shfl_xor(ssq, 2);
                ssq += __shfl_xor(ssq, 4); ssq += __shfl_xor(ssq, 8);
                const float inv = 1.f / fmaxf(sqrtf(ssq), 1e-12f);
                kqv[p].x = (short)f2bf(v.x * inv); kqv[p].y = (short)f2bf(v.y * inv);
                kqv[p].z = (short)f2bf(v.z * inv); kqv[p].w = (short)f2bf(v.w * inv);
            }
            {
                const int n0 = kt * 64 + sc;     // 4-aligned; N%4==0 -> whole-float4 guard
                float4 v = {0.f, 0.f, 0.f, 0.f};
                if (n0 < N) v = *(const float4*)(vtp + (size_t)row * N + n0);
                vqv[p].x = (short)f2bf(v.x); vqv[p].y = (short)f2bf(v.y);
                vqv[p].z = (short)f2bf(v.z); vqv[p].w = (short)f2bf(v.w);
            }
        }

        __syncthreads();   // previous tile's Ks/Vt reads complete
        #pragma unroll
        for (int p = 0; p < 4; ++p) {
            const int row = p * 16 + sr;
            const int cswz = sc ^ ((row & 7) << 3);
            *(short4v*)&Ks[row][cswz] = kqv[p];
            *(short4v*)&Vt[row][cswz] = vqv[p];
        }
        __syncthreads();

        // ---- S = Q K^T : 16q x 64kv per wave ----
        f32x4 s_acc[4] = {};
        #pragma unroll
        for (int kvb = 0; kvb < 4; ++kvb) {
            const int krow = kvb * 16 + l15;
            const int m = (krow & 7) << 3;
            const bf16x8 kf0 = *(const bf16x8*)&Ks[krow][(lg * 8) ^ m];
            const bf16x8 kf1 = *(const bf16x8*)&Ks[krow][(32 + lg * 8) ^ m];
            s_acc[kvb] = __builtin_amdgcn_mfma_f32_16x16x32_bf16(qf[0], kf0, s_acc[kvb], 0, 0, 0);
            s_acc[kvb] = __builtin_amdgcn_mfma_f32_16x16x32_bf16(qf[1], kf1, s_acc[kvb], 0, 0, 0);
        }

        // ---- P = exp(S) (masked), stage to Ss, accumulate denominator ----
        #pragma unroll
        for (int kvb = 0; kvb < 4; ++kvb) {
            const int kvg = kt * 64 + kvb * 16 + l15;
            const bool ok = kvg < N;
            #pragma unroll
            for (int r = 0; r < 4; ++r) {
                const float pv = ok ? __expf(s_acc[kvb][r]) : 0.f;
                const ushort pb = f2bf(pv);
                denom[r] += bf2f(pb);          // consistent with PV numerator
                const int qr = w * 16 + lg * 4 + r;
                Ss[qr][(kvb * 16 + l15) ^ ((qr & 7) << 3)] = pb;
            }
        }

        // ---- O += P V ----
        {
            const int prow = w * 16 + l15;
            const int mp = (prow & 7) << 3;
            const bf16x8 pf0 = *(const bf16x8*)&Ss[prow][(lg * 8) ^ mp];
            const bf16x8 pf1 = *(const bf16x8*)&Ss[prow][(32 + lg * 8) ^ mp];
            #pragma unroll
            for (int dt = 0; dt < 4; ++dt) {
                const int vrow = dt * 16 + l15;
                const int m = (vrow & 7) << 3;
                const bf16x8 vf0 = *(const bf16x8*)&Vt[vrow][(lg * 8) ^ m];
                const bf16x8 vf1 = *(const bf16x8*)&Vt[vrow][(32 + lg * 8) ^ m];
                o_acc[dt] = __builtin_amdgcn_mfma_f32_16x16x32_bf16(pf0, vf0, o_acc[dt], 0, 0, 0);
                o_acc[dt] = __builtin_amdgcn_mfma_f32_16x16x32_bf16(pf1, vf1, o_acc[dt], 0, 0, 0);
            }
        }
    }

    // ---- epilogue: reduce denoms over the 16 kv-lanes, normalize, store ----
    #pragma unroll
    for (int r = 0; r < 4; ++r) {
        float ds = denom[r];
        ds += __shfl_xor(ds, 1); ds += __shfl_xor(ds, 2);
        ds += __shfl_xor(ds, 4); ds += __shfl_xor(ds, 8);
        denom[r] = ds;
    }

    const int b_ = bh / H;
    const int h_ = bh % H;
    #pragma unroll
    for (int r = 0; r < 4; ++r) {
        const int n = qt * 64 + w * 16 + lg * 4 + r;
        if (n < N) {
            const float inv = 1.f / denom[r];
            #pragma unroll
            for (int dt = 0; dt < 4; ++dt)
                out[((size_t)b_ * N + n) * C + (h_ << 6) + dt * 16 + l15] =
                    o_acc[dt][r] * inv;
        }
    }
}

extern "C" void kernel_launch(void* const* d_in, const int* in_sizes, int n_in,
                              void* d_out, int out_size, void* d_ws, size_t ws_size,
                              hipStream_t stream) {
    const float* x  = (const float*)d_in[0];
    const float* Wq = (const float*)d_in[1];
    const float* bq = (const float*)d_in[2];
    float* out = (float*)d_out;
    float* ws  = (float*)d_ws;   // q[bh][n][d], k[bh][n][d], vT[bh][d][n]

    qkv_gemm_kernel<<<dim3((B * N) / 128, (3 * C) / 128), 256, 0, stream>>>(x, Wq, bq, ws);
    attn_kernel<<<dim3(25 * B * H), 256, 0, stream>>>(ws, out);
}

// Round 4
// 286.606 us; speedup vs baseline: 17.2981x; 2.6800x over previous
//
#include <hip/hip_runtime.h>

typedef __attribute__((ext_vector_type(8))) short bf16x8;
typedef __attribute__((ext_vector_type(4))) float f32x4;
typedef __attribute__((ext_vector_type(4))) short short4v;

namespace {
constexpr int B = 8;
constexpr int N = 1568;
constexpr int C = 768;
constexpr int H = 12;
constexpr int D = 64;
constexpr int M = B * N;                    // 12544 rows
constexpr long long QK = (long long)B * H * N * D;   // 9,633,792 elems/tensor
constexpr int NT = 25;
// ws layout (ushort elements): xb | Wb | q | k | vT
constexpr size_t OFF_XB = 0;
constexpr size_t OFF_WB = OFF_XB + (size_t)M * C;          // 9,633,792
constexpr size_t OFF_Q  = OFF_WB + (size_t)3 * C * C;      // +1,769,472
constexpr size_t OFF_K  = OFF_Q + (size_t)QK;
constexpr size_t OFF_VT = OFF_K + (size_t)QK;
}

__device__ __forceinline__ ushort f2bf(float f) {
    union { float f; unsigned u; } a; a.f = f;
    unsigned u = a.u;
    u += 0x7FFF + ((u >> 16) & 1);   // RNE
    return (ushort)(u >> 16);
}
__device__ __forceinline__ float bf2f(ushort s) {
    union { float f; unsigned u; } a; a.u = ((unsigned)s) << 16;
    return a.f;
}
__device__ __forceinline__ void gload16(const ushort* g, ushort* l) {
    __builtin_amdgcn_global_load_lds(
        (const __attribute__((address_space(1))) ushort*)g,
        (__attribute__((address_space(3))) ushort*)l, 16, 0, 0);
}

// ---------------------------------------------------------------------------
// Prepass: fp32 -> bf16 for x and W.
// ---------------------------------------------------------------------------
__global__ __launch_bounds__(256) void cvt_bf16_kernel(
    const float* __restrict__ x, const float* __restrict__ W,
    ushort* __restrict__ xb, ushort* __restrict__ wb)
{
    constexpr int NX = M * C / 4;        // 2,408,448
    constexpr int NW = 3 * C * C / 4;    // 442,368
    for (int i = blockIdx.x * blockDim.x + threadIdx.x; i < NX + NW;
         i += gridDim.x * blockDim.x) {
        float4 v; ushort* dst; int o;
        if (i < NX) { v = ((const float4*)x)[i]; dst = xb; o = i; }
        else        { v = ((const float4*)W)[i - NX]; dst = wb; o = i - NX; }
        short4v s;
        s.x = (short)f2bf(v.x); s.y = (short)f2bf(v.y);
        s.z = (short)f2bf(v.z); s.w = (short)f2bf(v.w);
        *(short4v*)(dst + (size_t)o * 4) = s;
    }
}

// ---------------------------------------------------------------------------
// QKV GEMM, bf16 MFMA (m97 structure). 128x128 tile, BK=64, 4 waves (2x2 of
// 64x64). global_load_lds w=16 with pre-swizzled global source; LDS reads
// XOR-unswizzle (T2): slot (R,c) holds element chunk c^(R&7)  -> 2-way free.
// Epilogue: q,k -> bf16 [bh][n][d] (scalar 2B); v -> bf16 [bh][d][n] packed
// 8B stores (fragment rows = 4 consecutive n, free transpose).
// ---------------------------------------------------------------------------
__global__ __launch_bounds__(256) void qkv_mfma_kernel(
    const ushort* __restrict__ xb, const ushort* __restrict__ Wb,
    const float* __restrict__ bias, ushort* __restrict__ qg,
    ushort* __restrict__ kg, ushort* __restrict__ vtg)
{
    __shared__ ushort Ab[128][64];
    __shared__ ushort Bb[128][64];

    const int tid = threadIdx.x;
    const int l = tid & 63;
    const int w = tid >> 6;
    const int l15 = l & 15, lg = l >> 4;

    // bijective XCD swizzle (nwg=1764, q=220, r=4)
    const int orig = blockIdx.x;
    const int xcd = orig & 7;
    const int base = (xcd < 4) ? xcd * 221 : 4 * 221 + (xcd - 4) * 220;
    const int wgid = base + (orig >> 3);
    const int mt = wgid / 18;
    const int jt = wgid - mt * 18;
    const int m0 = mt * 128;
    const int j0 = jt * 128;

    const int wr = w >> 1, wc = w & 1;
    const int Rr = l >> 3;       // staging sub-row 0..7
    const int cch = l & 7;       // staging chunk (8 ushorts)

    f32x4 acc[4][4] = {};

    for (int kb = 0; kb < C; kb += 64) {
        __syncthreads();
        #pragma unroll
        for (int i = 0; i < 4; ++i) {
            const int R = (w * 4 + i) * 8 + Rr;
            const int cg = (cch ^ (R & 7)) * 8;          // pre-swizzled source
            gload16(xb + (size_t)(m0 + R) * C + kb + cg, &Ab[0][0] + (w * 4 + i) * 512);
            gload16(Wb + (size_t)(j0 + R) * C + kb + cg, &Bb[0][0] + (w * 4 + i) * 512);
        }
        __syncthreads();

        #pragma unroll
        for (int kk = 0; kk < 2; ++kk) {
            bf16x8 af[4], bfr[4];
            #pragma unroll
            for (int t = 0; t < 4; ++t) {
                const int ra = wr * 64 + t * 16 + l15;
                af[t]  = *(const bf16x8*)&Ab[ra][((kk * 4 + lg) ^ (ra & 7)) * 8];
                const int rb = wc * 64 + t * 16 + l15;
                bfr[t] = *(const bf16x8*)&Bb[rb][((kk * 4 + lg) ^ (rb & 7)) * 8];
            }
            #pragma unroll
            for (int mi = 0; mi < 4; ++mi)
                #pragma unroll
                for (int nj = 0; nj < 4; ++nj)
                    acc[mi][nj] = __builtin_amdgcn_mfma_f32_16x16x32_bf16(
                        af[mi], bfr[nj], acc[mi][nj], 0, 0, 0);
        }
    }

    // epilogue: C/D layout col=lane&15, row=(lane>>4)*4+r  [verified m89/m91]
    const int sel = jt / 6;                  // uniform per block
    #pragma unroll
    for (int nj = 0; nj < 4; ++nj) {
        const int jcol = j0 + wc * 64 + nj * 16 + l15;
        const int rem = jcol - sel * C;
        const int h = rem >> 6, d = rem & 63;
        const float bb = bias[jcol];
        if (sel < 2) {
            ushort* dst = (sel == 0) ? qg : kg;
            #pragma unroll
            for (int mi = 0; mi < 4; ++mi) {
                const int mb = m0 + wr * 64 + mi * 16 + lg * 4;
                #pragma unroll
                for (int r = 0; r < 4; ++r) {
                    const int m = mb + r;
                    const int b_ = m / N, n_ = m - b_ * N;
                    dst[(((size_t)b_ * H + h) * N + n_) * D + d] =
                        f2bf(acc[mi][nj][r] + bb);
                }
            }
        } else {
            #pragma unroll
            for (int mi = 0; mi < 4; ++mi) {
                const int mb = m0 + wr * 64 + mi * 16 + lg * 4;   // 4-aligned, no b straddle
                const int b_ = mb / N, n_ = mb - b_ * N;
                short4v o;
                o.x = (short)f2bf(acc[mi][nj][0] + bb);
                o.y = (short)f2bf(acc[mi][nj][1] + bb);
                o.z = (short)f2bf(acc[mi][nj][2] + bb);
                o.w = (short)f2bf(acc[mi][nj][3] + bb);
                *(short4v*)&vtg[(((size_t)b_ * H + h) * D + d) * N + n_] = o;
            }
        }
    }
}

// ---------------------------------------------------------------------------
// Cosine attention, bf16 MFMA 16x16x32 (structure verified round 3).
// Inputs now bf16: q,k [bh][n][d]; v^T [bh][d][n].
// ---------------------------------------------------------------------------
__global__ __launch_bounds__(256) void attn_kernel(
    const ushort* __restrict__ qg, const ushort* __restrict__ kg,
    const ushort* __restrict__ vtg, float* __restrict__ out)
{
    __shared__ ushort Qs[64][64];
    __shared__ ushort Ks[64][64];
    __shared__ ushort Vt[64][64];
    __shared__ ushort Ss[64][64];

    const int tid = threadIdx.x;
    const int l   = tid & 63;
    const int w   = tid >> 6;
    const int l15 = l & 15;
    const int lg  = l >> 4;

    const int bid = blockIdx.x;
    const int qt  = (bid >> 3) % 25;
    const int bh  = (bid & 7) + 8 * ((bid >> 3) / 25);

    const ushort* qp  = qg  + (size_t)bh * N * D;
    const ushort* kp  = kg  + (size_t)bh * N * D;
    const ushort* vtp = vtg + (size_t)bh * D * N;

    const int sr = tid >> 4;
    const int sc = (tid & 15) << 2;

    // ---- stage Q (normalize in f32, store bf16, swizzled) ----
    #pragma unroll
    for (int p = 0; p < 4; ++p) {
        const int row = p * 16 + sr;
        const int n = qt * 64 + row;
        float qv[4] = {0.f, 0.f, 0.f, 0.f};
        if (n < N) {
            const short4v t = *(const short4v*)(qp + (size_t)n * D + sc);
            qv[0] = bf2f((ushort)t.x); qv[1] = bf2f((ushort)t.y);
            qv[2] = bf2f((ushort)t.z); qv[3] = bf2f((ushort)t.w);
        }
        float ssq = qv[0]*qv[0] + qv[1]*qv[1] + qv[2]*qv[2] + qv[3]*qv[3];
        ssq += __shfl_xor(ssq, 1); ssq += __shfl_xor(ssq, 2);
        ssq += __shfl_xor(ssq, 4); ssq += __shfl_xor(ssq, 8);
        const float inv = 1.f / fmaxf(sqrtf(ssq), 1e-12f);
        short4v o;
        o.x = (short)f2bf(qv[0] * inv); o.y = (short)f2bf(qv[1] * inv);
        o.z = (short)f2bf(qv[2] * inv); o.w = (short)f2bf(qv[3] * inv);
        *(short4v*)&Qs[row][sc ^ ((row & 7) << 3)] = o;
    }
    __syncthreads();

    bf16x8 qf[2];
    {
        const int qrow = w * 16 + l15;
        const int m = (qrow & 7) << 3;
        qf[0] = *(const bf16x8*)&Qs[qrow][(lg * 8) ^ m];
        qf[1] = *(const bf16x8*)&Qs[qrow][(32 + lg * 8) ^ m];
    }

    f32x4 o_acc[4] = {};
    float denom[4] = {0.f, 0.f, 0.f, 0.f};

    for (int kt = 0; kt < NT; ++kt) {
        short4v kqv[4], vqv[4];
        #pragma unroll
        for (int p = 0; p < 4; ++p) {
            const int row = p * 16 + sr;
            {
                const int n = kt * 64 + row;
                float kv[4] = {0.f, 0.f, 0.f, 0.f};
                if (n < N) {
                    const short4v t = *(const short4v*)(kp + (size_t)n * D + sc);
                    kv[0] = bf2f((ushort)t.x); kv[1] = bf2f((ushort)t.y);
                    kv[2] = bf2f((ushort)t.z); kv[3] = bf2f((ushort)t.w);
                }
                float ssq = kv[0]*kv[0] + kv[1]*kv[1] + kv[2]*kv[2] + kv[3]*kv[3];
                ssq += __shfl_xor(ssq, 1); ssq += __shfl_xor(ssq, 2);
                ssq += __shfl_xor(ssq, 4); ssq += __shfl_xor(ssq, 8);
                const float inv = 1.f / fmaxf(sqrtf(ssq), 1e-12f);
                kqv[p].x = (short)f2bf(kv[0] * inv); kqv[p].y = (short)f2bf(kv[1] * inv);
                kqv[p].z = (short)f2bf(kv[2] * inv); kqv[p].w = (short)f2bf(kv[3] * inv);
            }
            {
                const int n0 = kt * 64 + sc;     // 4-aligned, N%4==0
                short4v t = {0, 0, 0, 0};
                if (n0 < N) t = *(const short4v*)(vtp + (size_t)row * N + n0);
                vqv[p] = t;
            }
        }

        __syncthreads();
        #pragma unroll
        for (int p = 0; p < 4; ++p) {
            const int row = p * 16 + sr;
            const int cswz = sc ^ ((row & 7) << 3);
            *(short4v*)&Ks[row][cswz] = kqv[p];
            *(short4v*)&Vt[row][cswz] = vqv[p];
        }
        __syncthreads();

        // ---- S = Q K^T ----
        f32x4 s_acc[4] = {};
        #pragma unroll
        for (int kvb = 0; kvb < 4; ++kvb) {
            const int krow = kvb * 16 + l15;
            const int m = (krow & 7) << 3;
            const bf16x8 kf0 = *(const bf16x8*)&Ks[krow][(lg * 8) ^ m];
            const bf16x8 kf1 = *(const bf16x8*)&Ks[krow][(32 + lg * 8) ^ m];
            s_acc[kvb] = __builtin_amdgcn_mfma_f32_16x16x32_bf16(qf[0], kf0, s_acc[kvb], 0, 0, 0);
            s_acc[kvb] = __builtin_amdgcn_mfma_f32_16x16x32_bf16(qf[1], kf1, s_acc[kvb], 0, 0, 0);
        }

        // ---- P = exp(S), stage, denominator ----
        #pragma unroll
        for (int kvb = 0; kvb < 4; ++kvb) {
            const int kvg = kt * 64 + kvb * 16 + l15;
            const bool ok = kvg < N;
            #pragma unroll
            for (int r = 0; r < 4; ++r) {
                const float pv = ok ? __expf(s_acc[kvb][r]) : 0.f;
                const ushort pb = f2bf(pv);
                denom[r] += bf2f(pb);
                const int qr = w * 16 + lg * 4 + r;
                Ss[qr][(kvb * 16 + l15) ^ ((qr & 7) << 3)] = pb;
            }
        }

        // ---- O += P V ----
        {
            const int prow = w * 16 + l15;
            const int mp = (prow & 7) << 3;
            const bf16x8 pf0 = *(const bf16x8*)&Ss[prow][(lg * 8) ^ mp];
            const bf16x8 pf1 = *(const bf16x8*)&Ss[prow][(32 + lg * 8) ^ mp];
            #pragma unroll
            for (int dt = 0; dt < 4; ++dt) {
                const int vrow = dt * 16 + l15;
                const int m = (vrow & 7) << 3;
                const bf16x8 vf0 = *(const bf16x8*)&Vt[vrow][(lg * 8) ^ m];
                const bf16x8 vf1 = *(const bf16x8*)&Vt[vrow][(32 + lg * 8) ^ m];
                o_acc[dt] = __builtin_amdgcn_mfma_f32_16x16x32_bf16(pf0, vf0, o_acc[dt], 0, 0, 0);
                o_acc[dt] = __builtin_amdgcn_mfma_f32_16x16x32_bf16(pf1, vf1, o_acc[dt], 0, 0, 0);
            }
        }
    }

    #pragma unroll
    for (int r = 0; r < 4; ++r) {
        float ds = denom[r];
        ds += __shfl_xor(ds, 1); ds += __shfl_xor(ds, 2);
        ds += __shfl_xor(ds, 4); ds += __shfl_xor(ds, 8);
        denom[r] = ds;
    }

    const int b_ = bh / H;
    const int h_ = bh % H;
    #pragma unroll
    for (int r = 0; r < 4; ++r) {
        const int n = qt * 64 + w * 16 + lg * 4 + r;
        if (n < N) {
            const float inv = 1.f / denom[r];
            #pragma unroll
            for (int dt = 0; dt < 4; ++dt)
                out[((size_t)b_ * N + n) * C + (h_ << 6) + dt * 16 + l15] =
                    o_acc[dt][r] * inv;
        }
    }
}

extern "C" void kernel_launch(void* const* d_in, const int* in_sizes, int n_in,
                              void* d_out, int out_size, void* d_ws, size_t ws_size,
                              hipStream_t stream) {
    const float* x  = (const float*)d_in[0];
    const float* Wq = (const float*)d_in[1];
    const float* bq = (const float*)d_in[2];
    float* out = (float*)d_out;
    ushort* ws = (ushort*)d_ws;   // xb | Wb | q | k | vT  (~80.6 MB)

    ushort* xb  = ws + OFF_XB;
    ushort* wb  = ws + OFF_WB;
    ushort* qg  = ws + OFF_Q;
    ushort* kg  = ws + OFF_K;
    ushort* vtg = ws + OFF_VT;

    cvt_bf16_kernel<<<2048, 256, 0, stream>>>(x, Wq, xb, wb);
    qkv_mfma_kernel<<<(M / 128) * (3 * C / 128), 256, 0, stream>>>(xb, wb, bq, qg, kg, vtg);
    attn_kernel<<<25 * B * H, 256, 0, stream>>>(qg, kg, vtg, out);
}

// Round 5
// 222.591 us; speedup vs baseline: 22.2729x; 1.2876x over previous
//
#include <hip/hip_runtime.h>

typedef __attribute__((ext_vector_type(8))) short bf16x8;
typedef __attribute__((ext_vector_type(4))) float f32x4;
typedef __attribute__((ext_vector_type(4))) short short4v;

namespace {
constexpr int B = 8;
constexpr int N = 1568;
constexpr int NP = 1600;                 // padded rows for DMA staging
constexpr int C = 768;
constexpr int H = 12;
constexpr int D = 64;
constexpr int M = B * N;                 // 12544
constexpr int NT = 25;
constexpr size_t QKP = (size_t)B * H * NP * D;       // 9,830,400 elems
// ws layout (ushort): xb | Wb | q | k | vT   (all 16B-aligned offsets)
constexpr size_t OFF_XB = 0;
constexpr size_t OFF_WB = OFF_XB + (size_t)M * C;    // 9,633,792
constexpr size_t OFF_Q  = OFF_WB + (size_t)3 * C * C;
constexpr size_t OFF_K  = OFF_Q + QKP;
constexpr size_t OFF_VT = OFF_K + QKP;
}

__device__ __forceinline__ ushort f2bf(float f) {
    union { float f; unsigned u; } a; a.f = f;
    unsigned u = a.u;
    u += 0x7FFF + ((u >> 16) & 1);   // RNE
    return (ushort)(u >> 16);
}
__device__ __forceinline__ void gload16(const ushort* g, ushort* l) {
    __builtin_amdgcn_global_load_lds(
        (const __attribute__((address_space(1))) ushort*)g,
        (__attribute__((address_space(3))) ushort*)l, 16, 0, 0);
}

// ---------------------------------------------------------------------------
// Prepass: fp32 -> bf16 for x and W.
// ---------------------------------------------------------------------------
__global__ __launch_bounds__(256) void cvt_bf16_kernel(
    const float* __restrict__ x, const float* __restrict__ W,
    ushort* __restrict__ xb, ushort* __restrict__ wb)
{
    constexpr int NX = M * C / 4;
    constexpr int NW = 3 * C * C / 4;
    for (int i = blockIdx.x * blockDim.x + threadIdx.x; i < NX + NW;
         i += gridDim.x * blockDim.x) {
        float4 v; ushort* dst; int o;
        if (i < NX) { v = ((const float4*)x)[i]; dst = xb; o = i; }
        else        { v = ((const float4*)W)[i - NX]; dst = wb; o = i - NX; }
        short4v s;
        s.x = (short)f2bf(v.x); s.y = (short)f2bf(v.y);
        s.z = (short)f2bf(v.z); s.w = (short)f2bf(v.w);
        *(short4v*)(dst + (size_t)o * 4) = s;
    }
}

// ---------------------------------------------------------------------------
// QKV GEMM, bf16 MFMA, 128x128 BK=64 (m97 structure), global_load_lds w=16
// with pre-swizzled source. Epilogue: q,k rows L2-NORMALIZED in fp32
// (4 reg values + 16-lane shfl reduce = full d=0..63 row) then bf16 scatter
// to [bh][n(pad 1600)][d]; v -> bf16 [bh][d][n(pad)] packed 8B transposed
// stores (fragment rows = 4 consecutive n).
// ---------------------------------------------------------------------------
__global__ __launch_bounds__(256) void qkv_mfma_kernel(
    const ushort* __restrict__ xb, const ushort* __restrict__ Wb,
    const float* __restrict__ bias, ushort* __restrict__ qg,
    ushort* __restrict__ kg, ushort* __restrict__ vtg)
{
    __shared__ ushort Ab[128][64];
    __shared__ ushort Bb[128][64];

    const int tid = threadIdx.x;
    const int l = tid & 63;
    const int w = tid >> 6;
    const int l15 = l & 15, lg = l >> 4;

    // bijective XCD swizzle (nwg=1764, q=220, r=4)
    const int orig = blockIdx.x;
    const int xcd = orig & 7;
    const int base = (xcd < 4) ? xcd * 221 : 4 * 221 + (xcd - 4) * 220;
    const int wgid = base + (orig >> 3);
    const int mt = wgid / 18;
    const int jt = wgid - mt * 18;
    const int m0 = mt * 128;
    const int j0 = jt * 128;

    const int wr = w >> 1, wc = w & 1;
    const int Rr = l >> 3;
    const int cch = l & 7;

    f32x4 acc[4][4] = {};

    for (int kb = 0; kb < C; kb += 64) {
        __syncthreads();
        #pragma unroll
        for (int i = 0; i < 4; ++i) {
            const int R = (w * 4 + i) * 8 + Rr;
            const int cg = (cch ^ (R & 7)) * 8;
            gload16(xb + (size_t)(m0 + R) * C + kb + cg, &Ab[0][0] + (w * 4 + i) * 512);
            gload16(Wb + (size_t)(j0 + R) * C + kb + cg, &Bb[0][0] + (w * 4 + i) * 512);
        }
        __syncthreads();

        #pragma unroll
        for (int kk = 0; kk < 2; ++kk) {
            bf16x8 af[4], bfr[4];
            #pragma unroll
            for (int t = 0; t < 4; ++t) {
                const int ra = wr * 64 + t * 16 + l15;
                af[t]  = *(const bf16x8*)&Ab[ra][((kk * 4 + lg) ^ (ra & 7)) * 8];
                const int rb = wc * 64 + t * 16 + l15;
                bfr[t] = *(const bf16x8*)&Bb[rb][((kk * 4 + lg) ^ (rb & 7)) * 8];
            }
            #pragma unroll
            for (int mi = 0; mi < 4; ++mi)
                #pragma unroll
                for (int nj = 0; nj < 4; ++nj)
                    acc[mi][nj] = __builtin_amdgcn_mfma_f32_16x16x32_bf16(
                        af[mi], bfr[nj], acc[mi][nj], 0, 0, 0);
        }
    }

    // epilogue: C/D layout col=lane&15, row=(lane>>4)*4+r
    const int sel = jt / 6;                  // block never straddles sel (768/128=6)
    if (sel < 2) {
        ushort* dst = (sel == 0) ? qg : kg;
        const int jbase = j0 + wc * 64;      // one head's 64-col block per wave
        const int h = (jbase - sel * C) >> 6;
        float bbv[4];
        #pragma unroll
        for (int nj = 0; nj < 4; ++nj) bbv[nj] = bias[jbase + nj * 16 + l15];
        #pragma unroll
        for (int mi = 0; mi < 4; ++mi) {
            #pragma unroll
            for (int r = 0; r < 4; ++r) {
                const float v0 = acc[mi][0][r] + bbv[0];
                const float v1 = acc[mi][1][r] + bbv[1];
                const float v2 = acc[mi][2][r] + bbv[2];
                const float v3 = acc[mi][3][r] + bbv[3];
                float ssq = v0*v0 + v1*v1 + v2*v2 + v3*v3;
                ssq += __shfl_xor(ssq, 1); ssq += __shfl_xor(ssq, 2);
                ssq += __shfl_xor(ssq, 4); ssq += __shfl_xor(ssq, 8);
                const float inv = 1.f / fmaxf(sqrtf(ssq), 1e-12f);
                const int m = m0 + wr * 64 + mi * 16 + lg * 4 + r;
                const int b_ = m / N, n_ = m - b_ * N;
                ushort* o = dst + (((size_t)b_ * H + h) * NP + n_) * D + l15;
                o[0]  = f2bf(v0 * inv);
                o[16] = f2bf(v1 * inv);
                o[32] = f2bf(v2 * inv);
                o[48] = f2bf(v3 * inv);
            }
        }
    } else {
        #pragma unroll
        for (int nj = 0; nj < 4; ++nj) {
            const int jcol = j0 + wc * 64 + nj * 16 + l15;
            const int rem = jcol - 2 * C;
            const int h = rem >> 6, d = rem & 63;
            const float bb = bias[jcol];
            #pragma unroll
            for (int mi = 0; mi < 4; ++mi) {
                const int mb = m0 + wr * 64 + mi * 16 + lg * 4;   // 4-aligned
                const int b_ = mb / N, n_ = mb - b_ * N;
                short4v o;
                o.x = (short)f2bf(acc[mi][nj][0] + bb);
                o.y = (short)f2bf(acc[mi][nj][1] + bb);
                o.z = (short)f2bf(acc[mi][nj][2] + bb);
                o.w = (short)f2bf(acc[mi][nj][3] + bb);
                *(short4v*)&vtg[(((size_t)b_ * H + h) * D + d) * NP + n_] = o;
            }
        }
    }
}

// ---------------------------------------------------------------------------
// Cosine attention: q,k pre-normalized bf16. All staging via global_load_lds
// (pre-swizzled source, zero VALU). Double-buffered K/V, 2-phase pipeline:
// issue next tile's DMA, compute current, one __syncthreads (drains vmcnt).
// LDS 48 KiB -> 3 blocks/CU.
// ---------------------------------------------------------------------------
__global__ __launch_bounds__(256) void attn_kernel(
    const ushort* __restrict__ qg, const ushort* __restrict__ kg,
    const ushort* __restrict__ vtg, float* __restrict__ out)
{
    __shared__ ushort Qs[64 * 64];
    __shared__ ushort KsB[2][64 * 64];
    __shared__ ushort VtB[2][64 * 64];
    __shared__ ushort Ss[64 * 64];

    const int tid = threadIdx.x;
    const int l   = tid & 63;
    const int w   = tid >> 6;
    const int l15 = l & 15;
    const int lg  = l >> 4;

    const int bid = blockIdx.x;
    const int qt  = (bid >> 3) % 25;
    const int bh  = (bid & 7) + 8 * ((bid >> 3) / 25);

    const ushort* qp  = qg  + (size_t)bh * NP * D;
    const ushort* kp  = kg  + (size_t)bh * NP * D;
    const ushort* vtp = vtg + (size_t)bh * D * NP;

    const int rsub = l >> 3;                  // DMA row-sub 0..7
    const int cg   = ((l & 7) ^ rsub) << 3;   // pre-swizzled source chunk

    // ---- prologue: DMA Q + K/V tile 0 ----
    #pragma unroll
    for (int p = 0; p < 2; ++p) {
        const int row = p * 32 + w * 8 + rsub;
        const int ldsoff = (p * 32 + w * 8) * 64;
        gload16(qp + (size_t)(qt * 64 + row) * D + cg, Qs + ldsoff);
        gload16(kp + (size_t)row * D + cg,             KsB[0] + ldsoff);
        gload16(vtp + (size_t)row * NP + cg,           VtB[0] + ldsoff);
    }
    __syncthreads();

    bf16x8 qf[2];
    {
        const int qrow = w * 16 + l15;
        qf[0] = *(const bf16x8*)(Qs + qrow * 64 + ((lg       ^ (qrow & 7)) << 3));
        qf[1] = *(const bf16x8*)(Qs + qrow * 64 + (((4 + lg) ^ (qrow & 7)) << 3));
    }

    f32x4 o_acc[4] = {};
    float denom[4] = {0.f, 0.f, 0.f, 0.f};
    int cur = 0;

    for (int kt = 0; kt < NT; ++kt) {
        // issue next tile's DMA (targets buffer all waves finished last iter)
        if (kt + 1 < NT) {
            ushort* Kn = KsB[cur ^ 1];
            ushort* Vn = VtB[cur ^ 1];
            #pragma unroll
            for (int p = 0; p < 2; ++p) {
                const int row = p * 32 + w * 8 + rsub;
                const int ldsoff = (p * 32 + w * 8) * 64;
                gload16(kp + (size_t)((kt + 1) * 64 + row) * D + cg, Kn + ldsoff);
                gload16(vtp + (size_t)row * NP + (kt + 1) * 64 + cg, Vn + ldsoff);
            }
        }
        const ushort* Kc = KsB[cur];
        const ushort* Vc = VtB[cur];

        // ---- S = Q K^T ----
        f32x4 s_acc[4] = {};
        #pragma unroll
        for (int kvb = 0; kvb < 4; ++kvb) {
            const int krow = kvb * 16 + l15;
            const bf16x8 kf0 = *(const bf16x8*)(Kc + krow * 64 + ((lg       ^ (krow & 7)) << 3));
            const bf16x8 kf1 = *(const bf16x8*)(Kc + krow * 64 + (((4 + lg) ^ (krow & 7)) << 3));
            s_acc[kvb] = __builtin_amdgcn_mfma_f32_16x16x32_bf16(qf[0], kf0, s_acc[kvb], 0, 0, 0);
            s_acc[kvb] = __builtin_amdgcn_mfma_f32_16x16x32_bf16(qf[1], kf1, s_acc[kvb], 0, 0, 0);
        }

        // ---- P = exp(S) (mask pad cols), stage bf16, accumulate denom ----
        #pragma unroll
        for (int kvb = 0; kvb < 4; ++kvb) {
            const bool ok = kt * 64 + kvb * 16 + l15 < N;
            #pragma unroll
            for (int r = 0; r < 4; ++r) {
                const float pv = ok ? __expf(s_acc[kvb][r]) : 0.f;
                denom[r] += pv;
                const int qr = w * 16 + lg * 4 + r;
                Ss[qr * 64 + ((kvb * 16 + l15) ^ ((qr & 7) << 3))] = f2bf(pv);
            }
        }

        // ---- O += P V (Ss wave-private: no barrier needed) ----
        {
            const int prow = w * 16 + l15;
            const bf16x8 pf0 = *(const bf16x8*)(Ss + prow * 64 + ((lg       ^ (prow & 7)) << 3));
            const bf16x8 pf1 = *(const bf16x8*)(Ss + prow * 64 + (((4 + lg) ^ (prow & 7)) << 3));
            #pragma unroll
            for (int dt = 0; dt < 4; ++dt) {
                const int vrow = dt * 16 + l15;
                const bf16x8 vf0 = *(const bf16x8*)(Vc + vrow * 64 + ((lg       ^ (vrow & 7)) << 3));
                const bf16x8 vf1 = *(const bf16x8*)(Vc + vrow * 64 + (((4 + lg) ^ (vrow & 7)) << 3));
                o_acc[dt] = __builtin_amdgcn_mfma_f32_16x16x32_bf16(pf0, vf0, o_acc[dt], 0, 0, 0);
                o_acc[dt] = __builtin_amdgcn_mfma_f32_16x16x32_bf16(pf1, vf1, o_acc[dt], 0, 0, 0);
            }
        }

        __syncthreads();   // drains next-tile DMA (vmcnt) + all waves done with cur
        cur ^= 1;
    }

    // ---- epilogue: reduce denom, normalize, store ----
    #pragma unroll
    for (int r = 0; r < 4; ++r) {
        float ds = denom[r];
        ds += __shfl_xor(ds, 1); ds += __shfl_xor(ds, 2);
        ds += __shfl_xor(ds, 4); ds += __shfl_xor(ds, 8);
        denom[r] = ds;
    }

    const int b_ = bh / H;
    const int h_ = bh % H;
    #pragma unroll
    for (int r = 0; r < 4; ++r) {
        const int n = qt * 64 + w * 16 + lg * 4 + r;
        if (n < N) {
            const float inv = 1.f / denom[r];
            #pragma unroll
            for (int dt = 0; dt < 4; ++dt)
                out[((size_t)b_ * N + n) * C + (h_ << 6) + dt * 16 + l15] =
                    o_acc[dt][r] * inv;
        }
    }
}

extern "C" void kernel_launch(void* const* d_in, const int* in_sizes, int n_in,
                              void* d_out, int out_size, void* d_ws, size_t ws_size,
                              hipStream_t stream) {
    const float* x  = (const float*)d_in[0];
    const float* Wq = (const float*)d_in[1];
    const float* bq = (const float*)d_in[2];
    float* out = (float*)d_out;
    ushort* ws = (ushort*)d_ws;

    ushort* xb  = ws + OFF_XB;
    ushort* wb  = ws + OFF_WB;
    ushort* qg  = ws + OFF_Q;
    ushort* kg  = ws + OFF_K;
    ushort* vtg = ws + OFF_VT;

    cvt_bf16_kernel<<<2048, 256, 0, stream>>>(x, Wq, xb, wb);
    qkv_mfma_kernel<<<(M / 128) * (3 * C / 128), 256, 0, stream>>>(xb, wb, bq, qg, kg, vtg);
    attn_kernel<<<25 * B * H, 256, 0, stream>>>(qg, kg, vtg, out);
}

// Round 6
// 175.875 us; speedup vs baseline: 28.1889x; 1.2656x over previous
//
#include <hip/hip_runtime.h>

typedef __attribute__((ext_vector_type(8))) short bf16x8;
typedef __attribute__((ext_vector_type(4))) float f32x4;
typedef __attribute__((ext_vector_type(16))) float f32x16;
typedef __attribute__((ext_vector_type(4))) short short4v;

namespace {
constexpr int B = 8;
constexpr int N = 1568;
constexpr int NP = 1664;                 // padded rows: 13 q-tiles x 128
constexpr int C = 768;
constexpr int H = 12;
constexpr int D = 64;
constexpr int M = B * N;                 // 12544
constexpr int NT = 25;                   // kv tiles of 64
constexpr int QT = 13;                   // q tiles of 128
constexpr size_t QKP = (size_t)B * H * NP * D;
// ws layout (ushort): xb | Wb | q | k | vT
constexpr size_t OFF_XB = 0;
constexpr size_t OFF_WB = OFF_XB + (size_t)M * C;
constexpr size_t OFF_Q  = OFF_WB + (size_t)3 * C * C;
constexpr size_t OFF_K  = OFF_Q + QKP;
constexpr size_t OFF_VT = OFF_K + QKP;
}

__device__ __forceinline__ ushort f2bf(float f) {
    union { float f; unsigned u; } a; a.f = f;
    unsigned u = a.u;
    u += 0x7FFF + ((u >> 16) & 1);   // RNE
    return (ushort)(u >> 16);
}
__device__ __forceinline__ void gload16(const ushort* g, ushort* l) {
    __builtin_amdgcn_global_load_lds(
        (const __attribute__((address_space(1))) ushort*)g,
        (__attribute__((address_space(3))) ushort*)l, 16, 0, 0);
}
__device__ __forceinline__ unsigned cvtpk(float lo, float hi) {
    unsigned r;
    asm("v_cvt_pk_bf16_f32 %0, %1, %2" : "=v"(r) : "v"(lo), "v"(hi));
    return r;
}
__device__ __forceinline__ void plswap(unsigned &a, unsigned &b) {
    // a' = [a_lo32 | b_lo32], b' = [a_hi32 | b_hi32]
    asm("v_permlane32_swap_b32 %0, %1" : "+v"(a), "+v"(b));
}

// ---------------------------------------------------------------------------
// Prepass: fp32 -> bf16 for x and W.
// ---------------------------------------------------------------------------
__global__ __launch_bounds__(256) void cvt_bf16_kernel(
    const float* __restrict__ x, const float* __restrict__ W,
    ushort* __restrict__ xb, ushort* __restrict__ wb)
{
    constexpr int NX = M * C / 4;
    constexpr int NW = 3 * C * C / 4;
    for (int i = blockIdx.x * blockDim.x + threadIdx.x; i < NX + NW;
         i += gridDim.x * blockDim.x) {
        float4 v; ushort* dst; int o;
        if (i < NX) { v = ((const float4*)x)[i]; dst = xb; o = i; }
        else        { v = ((const float4*)W)[i - NX]; dst = wb; o = i - NX; }
        short4v s;
        s.x = (short)f2bf(v.x); s.y = (short)f2bf(v.y);
        s.z = (short)f2bf(v.z); s.w = (short)f2bf(v.w);
        *(short4v*)(dst + (size_t)o * 4) = s;
    }
}

// ---------------------------------------------------------------------------
// QKV GEMM, bf16 MFMA 128x128 BK=64 (m97 structure). Epilogue: q,k rows
// L2-normalized in fp32, scattered bf16 to [bh][n pad1664][d]; v -> bf16
// [bh][d][n pad1664] packed transposed stores.
// ---------------------------------------------------------------------------
__global__ __launch_bounds__(256) void qkv_mfma_kernel(
    const ushort* __restrict__ xb, const ushort* __restrict__ Wb,
    const float* __restrict__ bias, ushort* __restrict__ qg,
    ushort* __restrict__ kg, ushort* __restrict__ vtg)
{
    __shared__ __align__(16) ushort Ab[128][64];
    __shared__ __align__(16) ushort Bb[128][64];

    const int tid = threadIdx.x;
    const int l = tid & 63;
    const int w = tid >> 6;
    const int l15 = l & 15, lg = l >> 4;

    // bijective XCD swizzle (nwg=1764, q=220, r=4)
    const int orig = blockIdx.x;
    const int xcd = orig & 7;
    const int base = (xcd < 4) ? xcd * 221 : 4 * 221 + (xcd - 4) * 220;
    const int wgid = base + (orig >> 3);
    const int mt = wgid / 18;
    const int jt = wgid - mt * 18;
    const int m0 = mt * 128;
    const int j0 = jt * 128;

    const int wr = w >> 1, wc = w & 1;
    const int Rr = l >> 3;
    const int cch = l & 7;

    f32x4 acc[4][4] = {};

    for (int kb = 0; kb < C; kb += 64) {
        __syncthreads();
        #pragma unroll
        for (int i = 0; i < 4; ++i) {
            const int R = (w * 4 + i) * 8 + Rr;
            const int cg = (cch ^ (R & 7)) * 8;
            gload16(xb + (size_t)(m0 + R) * C + kb + cg, &Ab[0][0] + (w * 4 + i) * 512);
            gload16(Wb + (size_t)(j0 + R) * C + kb + cg, &Bb[0][0] + (w * 4 + i) * 512);
        }
        __syncthreads();

        #pragma unroll
        for (int kk = 0; kk < 2; ++kk) {
            bf16x8 af[4], bfr[4];
            #pragma unroll
            for (int t = 0; t < 4; ++t) {
                const int ra = wr * 64 + t * 16 + l15;
                af[t]  = *(const bf16x8*)&Ab[ra][((kk * 4 + lg) ^ (ra & 7)) * 8];
                const int rb = wc * 64 + t * 16 + l15;
                bfr[t] = *(const bf16x8*)&Bb[rb][((kk * 4 + lg) ^ (rb & 7)) * 8];
            }
            #pragma unroll
            for (int mi = 0; mi < 4; ++mi)
                #pragma unroll
                for (int nj = 0; nj < 4; ++nj)
                    acc[mi][nj] = __builtin_amdgcn_mfma_f32_16x16x32_bf16(
                        af[mi], bfr[nj], acc[mi][nj], 0, 0, 0);
        }
    }

    const int sel = jt / 6;
    if (sel < 2) {
        ushort* dst = (sel == 0) ? qg : kg;
        const int jbase = j0 + wc * 64;
        const int h = (jbase - sel * C) >> 6;
        float bbv[4];
        #pragma unroll
        for (int nj = 0; nj < 4; ++nj) bbv[nj] = bias[jbase + nj * 16 + l15];
        #pragma unroll
        for (int mi = 0; mi < 4; ++mi) {
            #pragma unroll
            for (int r = 0; r < 4; ++r) {
                const float v0 = acc[mi][0][r] + bbv[0];
                const float v1 = acc[mi][1][r] + bbv[1];
                const float v2 = acc[mi][2][r] + bbv[2];
                const float v3 = acc[mi][3][r] + bbv[3];
                float ssq = v0*v0 + v1*v1 + v2*v2 + v3*v3;
                ssq += __shfl_xor(ssq, 1); ssq += __shfl_xor(ssq, 2);
                ssq += __shfl_xor(ssq, 4); ssq += __shfl_xor(ssq, 8);
                const float inv = 1.f / fmaxf(sqrtf(ssq), 1e-12f);
                const int m = m0 + wr * 64 + mi * 16 + lg * 4 + r;
                const int b_ = m / N, n_ = m - b_ * N;
                ushort* o = dst + (((size_t)b_ * H + h) * NP + n_) * D + l15;
                o[0]  = f2bf(v0 * inv);
                o[16] = f2bf(v1 * inv);
                o[32] = f2bf(v2 * inv);
                o[48] = f2bf(v3 * inv);
            }
        }
    } else {
        #pragma unroll
        for (int nj = 0; nj < 4; ++nj) {
            const int jcol = j0 + wc * 64 + nj * 16 + l15;
            const int rem = jcol - 2 * C;
            const int h = rem >> 6, d = rem & 63;
            const float bb = bias[jcol];
            #pragma unroll
            for (int mi = 0; mi < 4; ++mi) {
                const int mb = m0 + wr * 64 + mi * 16 + lg * 4;
                const int b_ = mb / N, n_ = mb - b_ * N;
                short4v o;
                o.x = (short)f2bf(acc[mi][nj][0] + bb);
                o.y = (short)f2bf(acc[mi][nj][1] + bb);
                o.z = (short)f2bf(acc[mi][nj][2] + bb);
                o.w = (short)f2bf(acc[mi][nj][3] + bb);
                *(short4v*)&vtg[(((size_t)b_ * H + h) * D + d) * NP + n_] = o;
            }
        }
    }
}

// ---------------------------------------------------------------------------
// Cosine attention, swapped-QK^T 32x32x16 with in-register softmax (T12).
// Block = (bh, 128-q-tile); wave w owns q rows w*32..w*32+31.
// QK: mfma(A=K, B=Q) -> S^T fragment: q = lane&31 (lane-local P-row),
//   kv = (reg&3)+8*(reg>>2)+4*(lane>>5)  [C/D layout verified m74/m101].
// P: exp in f32, cvt_pk_bf16 pairs, permlane32_swap -> PV A-fragments
//   (no LDS round-trip). PV: mfma(A=P, B=V^T rows from LDS).
// kt=24 tail: kv_rel 32..63 all pad -> uniform skip of fragment 1.
// LDS 48 KiB (Q 16K + K/V dbuf 32K) -> 3 blocks/CU.
// ---------------------------------------------------------------------------
__global__ __launch_bounds__(256) void attn_kernel(
    const ushort* __restrict__ qg, const ushort* __restrict__ kg,
    const ushort* __restrict__ vtg, float* __restrict__ out)
{
    __shared__ __align__(16) ushort Qs[128 * 64];
    __shared__ __align__(16) ushort KsB[2][64 * 64];
    __shared__ __align__(16) ushort VtB[2][64 * 64];

    const int tid = threadIdx.x;
    const int l   = tid & 63;
    const int w   = tid >> 6;
    const int l31 = l & 31;
    const int hi  = l >> 5;

    const int bid = blockIdx.x;
    const int grp = bid >> 3;                 // 0..155
    const int qt  = grp % QT;
    const int bh  = (bid & 7) + 8 * (grp / QT);

    const ushort* qp  = qg  + (size_t)bh * NP * D;
    const ushort* kp  = kg  + (size_t)bh * NP * D;
    const ushort* vtp = vtg + (size_t)bh * D * NP;

    const int rsub = l >> 3;                  // row&7 of the DMA row
    const int cg   = ((l & 7) ^ rsub) << 3;   // pre-swizzled source chunk

    // ---- prologue DMA: Q tile (128 rows), K/V tile 0 ----
    #pragma unroll
    for (int p = 0; p < 4; ++p) {
        const int rb = p * 32 + w * 8;
        gload16(qp + (size_t)(qt * 128 + rb + rsub) * D + cg, Qs + rb * 64);
    }
    #pragma unroll
    for (int p = 0; p < 2; ++p) {
        const int rb = p * 32 + w * 8;
        gload16(kp + (size_t)(rb + rsub) * D + cg, KsB[0] + rb * 64);
        gload16(vtp + (size_t)(rb + rsub) * NP + cg, VtB[0] + rb * 64);
    }
    __syncthreads();

    // Q fragments (B-operand): lane holds Q[q=w*32+l31][d = 16*ds + hi*8 ..+8]
    bf16x8 qf[4];
    {
        const int qrow = w * 32 + l31;
        #pragma unroll
        for (int ds = 0; ds < 4; ++ds) {
            const int ch = (2 * ds + hi) ^ (qrow & 7);
            qf[ds] = *(const bf16x8*)(Qs + qrow * 64 + ch * 8);
        }
    }

    f32x16 o_acc[2] = {};
    float denom = 0.f;
    int cur = 0;

    for (int kt = 0; kt < NT; ++kt) {
        // issue next tile's DMA (lands before the end-of-iter barrier)
        if (kt + 1 < NT) {
            ushort* Kn = KsB[cur ^ 1];
            ushort* Vn = VtB[cur ^ 1];
            #pragma unroll
            for (int p = 0; p < 2; ++p) {
                const int rb = p * 32 + w * 8;
                gload16(kp + (size_t)((kt + 1) * 64 + rb + rsub) * D + cg, Kn + rb * 64);
                gload16(vtp + (size_t)(rb + rsub) * NP + (kt + 1) * 64 + cg, Vn + rb * 64);
            }
        }
        const ushort* Kc = KsB[cur];
        const ushort* Vc = VtB[cur];

        // ---- S^T = K Q (per 32-kv fragment), exp, pack ----
        unsigned pw[16];
        #pragma unroll
        for (int f = 0; f < 2; ++f) {
            if (f == 1 && kt == NT - 1) {
                #pragma unroll
                for (int i = 0; i < 8; ++i) pw[8 + i] = 0;   // pad kv rows
            } else {
                f32x16 st = {};
                #pragma unroll
                for (int ds = 0; ds < 4; ++ds) {
                    const int krow = f * 32 + l31;
                    const int ch = (2 * ds + hi) ^ (krow & 7);
                    const bf16x8 kf = *(const bf16x8*)(Kc + krow * 64 + ch * 8);
                    st = __builtin_amdgcn_mfma_f32_32x32x16_bf16(kf, qf[ds], st, 0, 0, 0);
                }
                float p[16];
                #pragma unroll
                for (int r = 0; r < 16; ++r) p[r] = __expf(st[r]);
                const float t =
                    (((p[0]+p[1])+(p[2]+p[3])) + ((p[4]+p[5])+(p[6]+p[7]))) +
                    (((p[8]+p[9])+(p[10]+p[11])) + ((p[12]+p[13])+(p[14]+p[15])));
                denom += t;
                #pragma unroll
                for (int i = 0; i < 8; ++i)
                    pw[f * 8 + i] = cvtpk(p[2 * i], p[2 * i + 1]);
            }
        }

        // ---- redistribute: words -> PV A-fragments (T12 permlane recipe) ----
        #pragma unroll
        for (int q4 = 0; q4 < 4; ++q4) {
            plswap(pw[q4 * 4 + 0], pw[q4 * 4 + 2]);
            plswap(pw[q4 * 4 + 1], pw[q4 * 4 + 3]);
        }
        // pa[ks] = {pw[4ks..4ks+3]}: A[q=l31][kv = 16*ks + hi*8 + j]

        // ---- O += P V ----
        #pragma unroll
        for (int dt = 0; dt < 2; ++dt) {
            #pragma unroll
            for (int ks = 0; ks < 4; ++ks) {
                const int vrow = dt * 32 + l31;
                const int ch = (2 * ks + hi) ^ (vrow & 7);
                const bf16x8 vf = *(const bf16x8*)(Vc + vrow * 64 + ch * 8);
                union { unsigned u[4]; bf16x8 v; } A;
                A.u[0] = pw[ks * 4 + 0]; A.u[1] = pw[ks * 4 + 1];
                A.u[2] = pw[ks * 4 + 2]; A.u[3] = pw[ks * 4 + 3];
                o_acc[dt] = __builtin_amdgcn_mfma_f32_32x32x16_bf16(
                    A.v, vf, o_acc[dt], 0, 0, 0);
            }
        }

        __syncthreads();   // drains next-tile DMA; all waves done with cur
        cur ^= 1;
    }

    // ---- epilogue ----
    denom += __shfl_xor(denom, 32);          // combine the two hi-halves
    float* dn = (float*)Qs;                  // reuse Q LDS (Q frags long read)
    if (hi == 0) dn[w * 32 + l31] = 1.f / denom;
    __syncthreads();

    const int b_ = bh / H;
    const int h_ = bh % H;
    #pragma unroll
    for (int g = 0; g < 4; ++g) {
        const f32x4 inv4 = *(const f32x4*)&dn[w * 32 + g * 8 + hi * 4];
        #pragma unroll
        for (int r3 = 0; r3 < 4; ++r3) {
            const int n = qt * 128 + w * 32 + g * 8 + hi * 4 + r3;
            if (n < N) {
                const float iv = inv4[r3];
                #pragma unroll
                for (int dt = 0; dt < 2; ++dt)
                    out[((size_t)b_ * N + n) * C + (h_ << 6) + dt * 32 + l31] =
                        o_acc[dt][g * 4 + r3] * iv;
            }
        }
    }
}

extern "C" void kernel_launch(void* const* d_in, const int* in_sizes, int n_in,
                              void* d_out, int out_size, void* d_ws, size_t ws_size,
                              hipStream_t stream) {
    const float* x  = (const float*)d_in[0];
    const float* Wq = (const float*)d_in[1];
    const float* bq = (const float*)d_in[2];
    float* out = (float*)d_out;
    ushort* ws = (ushort*)d_ws;

    ushort* xb  = ws + OFF_XB;
    ushort* wb  = ws + OFF_WB;
    ushort* qg  = ws + OFF_Q;
    ushort* kg  = ws + OFF_K;
    ushort* vtg = ws + OFF_VT;

    cvt_bf16_kernel<<<2048, 256, 0, stream>>>(x, Wq, xb, wb);
    qkv_mfma_kernel<<<(M / 128) * (3 * C / 128), 256, 0, stream>>>(xb, wb, bq, qg, kg, vtg);
    attn_kernel<<<QT * B * H, 256, 0, stream>>>(qg, kg, vtg, out);
}

// Round 7
// 171.525 us; speedup vs baseline: 28.9039x; 1.0254x over previous
//
#include <hip/hip_runtime.h>

typedef __attribute__((ext_vector_type(8))) short bf16x8;
typedef __attribute__((ext_vector_type(4))) float f32x4;
typedef __attribute__((ext_vector_type(16))) float f32x16;
typedef __attribute__((ext_vector_type(4))) short short4v;

namespace {
constexpr int B = 8;
constexpr int N = 1568;
constexpr int NP = 1664;                 // padded rows: 13 q-tiles x 128
constexpr int C = 768;
constexpr int H = 12;
constexpr int D = 64;
constexpr int M = B * N;                 // 12544
constexpr int NT = 25;                   // kv tiles of 64
constexpr int QT = 13;                   // q tiles of 128
constexpr size_t QKP = (size_t)B * H * NP * D;
// ws layout (ushort): xb | Wb | q | k | vT
constexpr size_t OFF_XB = 0;
constexpr size_t OFF_WB = OFF_XB + (size_t)M * C;
constexpr size_t OFF_Q  = OFF_WB + (size_t)3 * C * C;
constexpr size_t OFF_K  = OFF_Q + QKP;
constexpr size_t OFF_VT = OFF_K + QKP;
constexpr float LOG2E = 1.44269504088896f;
}

__device__ __forceinline__ ushort f2bf(float f) {
    union { float f; unsigned u; } a; a.f = f;
    unsigned u = a.u;
    u += 0x7FFF + ((u >> 16) & 1);   // RNE
    return (ushort)(u >> 16);
}
__device__ __forceinline__ void gload16(const ushort* g, ushort* l) {
    __builtin_amdgcn_global_load_lds(
        (const __attribute__((address_space(1))) ushort*)g,
        (__attribute__((address_space(3))) ushort*)l, 16, 0, 0);
}
__device__ __forceinline__ unsigned cvtpk(float lo, float hi) {
    unsigned r;
    asm("v_cvt_pk_bf16_f32 %0, %1, %2" : "=v"(r) : "v"(lo), "v"(hi));
    return r;
}
__device__ __forceinline__ void plswap(unsigned &a, unsigned &b) {
    asm("v_permlane32_swap_b32 %0, %1" : "+v"(a), "+v"(b));
}

// ---------------------------------------------------------------------------
// Prepass: fp32 -> bf16 for x and W.
// ---------------------------------------------------------------------------
__global__ __launch_bounds__(256) void cvt_bf16_kernel(
    const float* __restrict__ x, const float* __restrict__ W,
    ushort* __restrict__ xb, ushort* __restrict__ wb)
{
    constexpr int NX = M * C / 4;
    constexpr int NW = 3 * C * C / 4;
    for (int i = blockIdx.x * blockDim.x + threadIdx.x; i < NX + NW;
         i += gridDim.x * blockDim.x) {
        float4 v; ushort* dst; int o;
        if (i < NX) { v = ((const float4*)x)[i]; dst = xb; o = i; }
        else        { v = ((const float4*)W)[i - NX]; dst = wb; o = i - NX; }
        short4v s;
        s.x = (short)f2bf(v.x); s.y = (short)f2bf(v.y);
        s.z = (short)f2bf(v.z); s.w = (short)f2bf(v.w);
        *(short4v*)(dst + (size_t)o * 4) = s;
    }
}

// ---------------------------------------------------------------------------
// QKV GEMM, bf16 MFMA 128x128 BK=64. Epilogue: q rows scaled by
// LOG2E/||q|| (exp2 fold), k rows by 1/||k||; bf16 scatter to
// [bh][n pad1664][d]; v -> [bh][d][n pad1664] packed transposed stores.
// ---------------------------------------------------------------------------
__global__ __launch_bounds__(256) void qkv_mfma_kernel(
    const ushort* __restrict__ xb, const ushort* __restrict__ Wb,
    const float* __restrict__ bias, ushort* __restrict__ qg,
    ushort* __restrict__ kg, ushort* __restrict__ vtg)
{
    __shared__ __align__(16) ushort Ab[128][64];
    __shared__ __align__(16) ushort Bb[128][64];

    const int tid = threadIdx.x;
    const int l = tid & 63;
    const int w = tid >> 6;
    const int l15 = l & 15, lg = l >> 4;

    // bijective XCD swizzle (nwg=1764, q=220, r=4)
    const int orig = blockIdx.x;
    const int xcd = orig & 7;
    const int base = (xcd < 4) ? xcd * 221 : 4 * 221 + (xcd - 4) * 220;
    const int wgid = base + (orig >> 3);
    const int mt = wgid / 18;
    const int jt = wgid - mt * 18;
    const int m0 = mt * 128;
    const int j0 = jt * 128;

    const int wr = w >> 1, wc = w & 1;
    const int Rr = l >> 3;
    const int cch = l & 7;

    f32x4 acc[4][4] = {};

    for (int kb = 0; kb < C; kb += 64) {
        __syncthreads();
        #pragma unroll
        for (int i = 0; i < 4; ++i) {
            const int R = (w * 4 + i) * 8 + Rr;
            const int cg = (cch ^ (R & 7)) * 8;
            gload16(xb + (size_t)(m0 + R) * C + kb + cg, &Ab[0][0] + (w * 4 + i) * 512);
            gload16(Wb + (size_t)(j0 + R) * C + kb + cg, &Bb[0][0] + (w * 4 + i) * 512);
        }
        __syncthreads();

        #pragma unroll
        for (int kk = 0; kk < 2; ++kk) {
            bf16x8 af[4], bfr[4];
            #pragma unroll
            for (int t = 0; t < 4; ++t) {
                const int ra = wr * 64 + t * 16 + l15;
                af[t]  = *(const bf16x8*)&Ab[ra][((kk * 4 + lg) ^ (ra & 7)) * 8];
                const int rb = wc * 64 + t * 16 + l15;
                bfr[t] = *(const bf16x8*)&Bb[rb][((kk * 4 + lg) ^ (rb & 7)) * 8];
            }
            #pragma unroll
            for (int mi = 0; mi < 4; ++mi)
                #pragma unroll
                for (int nj = 0; nj < 4; ++nj)
                    acc[mi][nj] = __builtin_amdgcn_mfma_f32_16x16x32_bf16(
                        af[mi], bfr[nj], acc[mi][nj], 0, 0, 0);
        }
    }

    const int sel = jt / 6;
    if (sel < 2) {
        ushort* dst = (sel == 0) ? qg : kg;
        const float scl = (sel == 0) ? LOG2E : 1.f;
        const int jbase = j0 + wc * 64;
        const int h = (jbase - sel * C) >> 6;
        float bbv[4];
        #pragma unroll
        for (int nj = 0; nj < 4; ++nj) bbv[nj] = bias[jbase + nj * 16 + l15];
        #pragma unroll
        for (int mi = 0; mi < 4; ++mi) {
            #pragma unroll
            for (int r = 0; r < 4; ++r) {
                const float v0 = acc[mi][0][r] + bbv[0];
                const float v1 = acc[mi][1][r] + bbv[1];
                const float v2 = acc[mi][2][r] + bbv[2];
                const float v3 = acc[mi][3][r] + bbv[3];
                float ssq = v0*v0 + v1*v1 + v2*v2 + v3*v3;
                ssq += __shfl_xor(ssq, 1); ssq += __shfl_xor(ssq, 2);
                ssq += __shfl_xor(ssq, 4); ssq += __shfl_xor(ssq, 8);
                const float inv = scl / fmaxf(sqrtf(ssq), 1e-12f);
                const int m = m0 + wr * 64 + mi * 16 + lg * 4 + r;
                const int b_ = m / N, n_ = m - b_ * N;
                ushort* o = dst + (((size_t)b_ * H + h) * NP + n_) * D + l15;
                o[0]  = f2bf(v0 * inv);
                o[16] = f2bf(v1 * inv);
                o[32] = f2bf(v2 * inv);
                o[48] = f2bf(v3 * inv);
            }
        }
    } else {
        #pragma unroll
        for (int nj = 0; nj < 4; ++nj) {
            const int jcol = j0 + wc * 64 + nj * 16 + l15;
            const int rem = jcol - 2 * C;
            const int h = rem >> 6, d = rem & 63;
            const float bb = bias[jcol];
            #pragma unroll
            for (int mi = 0; mi < 4; ++mi) {
                const int mb = m0 + wr * 64 + mi * 16 + lg * 4;
                const int b_ = mb / N, n_ = mb - b_ * N;
                short4v o;
                o.x = (short)f2bf(acc[mi][nj][0] + bb);
                o.y = (short)f2bf(acc[mi][nj][1] + bb);
                o.z = (short)f2bf(acc[mi][nj][2] + bb);
                o.w = (short)f2bf(acc[mi][nj][3] + bb);
                *(short4v*)&vtg[(((size_t)b_ * H + h) * D + d) * NP + n_] = o;
            }
        }
    }
}

// ---------------------------------------------------------------------------
// Cosine attention, swapped-QK^T 32x32x16 + in-register softmax (T12).
// Q fragments loaded straight from global to registers (no Q LDS).
// K/V double-buffered in LDS (exactly 32 KiB -> 5 blocks/CU; 1248-block
// grid fully resident). exp2 on pre-scaled scores. setprio around MFMA.
// ---------------------------------------------------------------------------
__global__ __launch_bounds__(256) void attn_kernel(
    const ushort* __restrict__ qg, const ushort* __restrict__ kg,
    const ushort* __restrict__ vtg, float* __restrict__ out)
{
    __shared__ __align__(16) ushort KsB[2][64 * 64];
    __shared__ __align__(16) ushort VtB[2][64 * 64];

    const int tid = threadIdx.x;
    const int l   = tid & 63;
    const int w   = tid >> 6;
    const int l31 = l & 31;
    const int hi  = l >> 5;

    const int bid = blockIdx.x;
    const int grp = bid >> 3;                 // 0..155
    const int qt  = grp % QT;
    const int bh  = (bid & 7) + 8 * (grp / QT);

    const ushort* qp  = qg  + (size_t)bh * NP * D;
    const ushort* kp  = kg  + (size_t)bh * NP * D;
    const ushort* vtp = vtg + (size_t)bh * D * NP;

    const int rsub = l >> 3;
    const int cg   = ((l & 7) ^ rsub) << 3;   // pre-swizzled source chunk

    // ---- Q fragments straight from global (logical d-order) ----
    bf16x8 qf[4];
    {
        const ushort* qr = qp + (size_t)(qt * 128 + w * 32 + l31) * D + hi * 8;
        #pragma unroll
        for (int ds = 0; ds < 4; ++ds)
            qf[ds] = *(const bf16x8*)(qr + ds * 16);
    }

    // ---- prologue DMA: K/V tile 0 ----
    #pragma unroll
    for (int p = 0; p < 2; ++p) {
        const int rb = p * 32 + w * 8;
        gload16(kp + (size_t)(rb + rsub) * D + cg, KsB[0] + rb * 64);
        gload16(vtp + (size_t)(rb + rsub) * NP + cg, VtB[0] + rb * 64);
    }
    __syncthreads();

    f32x16 o_acc[2] = {};
    float denom = 0.f;
    int cur = 0;

    for (int kt = 0; kt < NT; ++kt) {
        if (kt + 1 < NT) {
            ushort* Kn = KsB[cur ^ 1];
            ushort* Vn = VtB[cur ^ 1];
            #pragma unroll
            for (int p = 0; p < 2; ++p) {
                const int rb = p * 32 + w * 8;
                gload16(kp + (size_t)((kt + 1) * 64 + rb + rsub) * D + cg, Kn + rb * 64);
                gload16(vtp + (size_t)(rb + rsub) * NP + (kt + 1) * 64 + cg, Vn + rb * 64);
            }
        }
        const ushort* Kc = KsB[cur];
        const ushort* Vc = VtB[cur];

        // ---- S^T = K Q (scores pre-scaled by log2e), exp2, pack ----
        unsigned pw[16];
        #pragma unroll
        for (int f = 0; f < 2; ++f) {
            if (f == 1 && kt == NT - 1) {
                #pragma unroll
                for (int i = 0; i < 8; ++i) pw[8 + i] = 0;   // pad kv rows
            } else {
                f32x16 st = {};
                __builtin_amdgcn_s_setprio(1);
                #pragma unroll
                for (int ds = 0; ds < 4; ++ds) {
                    const int krow = f * 32 + l31;
                    const int ch = (2 * ds + hi) ^ (krow & 7);
                    const bf16x8 kf = *(const bf16x8*)(Kc + krow * 64 + ch * 8);
                    st = __builtin_amdgcn_mfma_f32_32x32x16_bf16(kf, qf[ds], st, 0, 0, 0);
                }
                __builtin_amdgcn_s_setprio(0);
                float p[16];
                #pragma unroll
                for (int r = 0; r < 16; ++r) p[r] = __builtin_amdgcn_exp2f(st[r]);
                const float t =
                    (((p[0]+p[1])+(p[2]+p[3])) + ((p[4]+p[5])+(p[6]+p[7]))) +
                    (((p[8]+p[9])+(p[10]+p[11])) + ((p[12]+p[13])+(p[14]+p[15])));
                denom += t;
                #pragma unroll
                for (int i = 0; i < 8; ++i)
                    pw[f * 8 + i] = cvtpk(p[2 * i], p[2 * i + 1]);
            }
        }

        // ---- redistribute: words -> PV A-fragments (T12 permlane recipe) ----
        #pragma unroll
        for (int q4 = 0; q4 < 4; ++q4) {
            plswap(pw[q4 * 4 + 0], pw[q4 * 4 + 2]);
            plswap(pw[q4 * 4 + 1], pw[q4 * 4 + 3]);
        }

        // ---- O += P V ----
        __builtin_amdgcn_s_setprio(1);
        #pragma unroll
        for (int dt = 0; dt < 2; ++dt) {
            #pragma unroll
            for (int ks = 0; ks < 4; ++ks) {
                const int vrow = dt * 32 + l31;
                const int ch = (2 * ks + hi) ^ (vrow & 7);
                const bf16x8 vf = *(const bf16x8*)(Vc + vrow * 64 + ch * 8);
                union { unsigned u[4]; bf16x8 v; } A;
                A.u[0] = pw[ks * 4 + 0]; A.u[1] = pw[ks * 4 + 1];
                A.u[2] = pw[ks * 4 + 2]; A.u[3] = pw[ks * 4 + 3];
                o_acc[dt] = __builtin_amdgcn_mfma_f32_32x32x16_bf16(
                    A.v, vf, o_acc[dt], 0, 0, 0);
            }
        }
        __builtin_amdgcn_s_setprio(0);

        __syncthreads();   // drains next-tile DMA; all waves done with cur
        cur ^= 1;
    }

    // ---- epilogue: reduce denom, broadcast via (freed) K LDS ----
    denom += __shfl_xor(denom, 32);
    float* dn = (float*)&KsB[0][0];
    if (hi == 0) dn[w * 32 + l31] = 1.f / denom;
    __syncthreads();

    const int b_ = bh / H;
    const int h_ = bh % H;
    #pragma unroll
    for (int g = 0; g < 4; ++g) {
        const f32x4 inv4 = *(const f32x4*)&dn[w * 32 + g * 8 + hi * 4];
        #pragma unroll
        for (int r3 = 0; r3 < 4; ++r3) {
            const int n = qt * 128 + w * 32 + g * 8 + hi * 4 + r3;
            if (n < N) {
                const float iv = inv4[r3];
                #pragma unroll
                for (int dt = 0; dt < 2; ++dt)
                    out[((size_t)b_ * N + n) * C + (h_ << 6) + dt * 32 + l31] =
                        o_acc[dt][g * 4 + r3] * iv;
            }
        }
    }
}

extern "C" void kernel_launch(void* const* d_in, const int* in_sizes, int n_in,
                              void* d_out, int out_size, void* d_ws, size_t ws_size,
                              hipStream_t stream) {
    const float* x  = (const float*)d_in[0];
    const float* Wq = (const float*)d_in[1];
    const float* bq = (const float*)d_in[2];
    float* out = (float*)d_out;
    ushort* ws = (ushort*)d_ws;

    ushort* xb  = ws + OFF_XB;
    ushort* wb  = ws + OFF_WB;
    ushort* qg  = ws + OFF_Q;
    ushort* kg  = ws + OFF_K;
    ushort* vtg = ws + OFF_VT;

    cvt_bf16_kernel<<<2048, 256, 0, stream>>>(x, Wq, xb, wb);
    qkv_mfma_kernel<<<(M / 128) * (3 * C / 128), 256, 0, stream>>>(xb, wb, bq, qg, kg, vtg);
    attn_kernel<<<QT * B * H, 256, 0, stream>>>(qg, kg, vtg, out);
}